// Round 8
// baseline (268.548 us; speedup 1.0000x reference)
//
#include <hip/hip_runtime.h>
#include <stdint.h>

#define B_ 4
#define S_ 2048
#define D_ 1024
#define H_ 16
#define HD_ 64

typedef __attribute__((ext_vector_type(8))) __bf16          bf16x8;
typedef __attribute__((ext_vector_type(8))) unsigned short  u16x8;
typedef __attribute__((ext_vector_type(4))) unsigned short  u16x4;
typedef __attribute__((ext_vector_type(4))) float           f32x4;
typedef __attribute__((ext_vector_type(16))) float          f32x16;
typedef unsigned short u16;
typedef unsigned int   u32;
typedef unsigned long long u64;

union BF8 { u16x8 u; bf16x8 b; u32 w[4]; };

__device__ __forceinline__ u16 f2bf(float f) {
  union { float f; uint32_t u; } v; v.f = f;
  uint32_t r = (v.u + 0x7FFFu + ((v.u >> 16) & 1u)) >> 16;  // RNE
  return (u16)r;
}

__device__ __forceinline__ u32 cvtpk(float lo, float hi) {
  u32 r;
  asm("v_cvt_pk_bf16_f32 %0, %1, %2" : "=v"(r) : "v"(lo), "v"(hi));
  return r;
}

// raw exp2: single v_exp_f32
__device__ __forceinline__ float fexp2(float x) {
  float r;
  asm("v_exp_f32 %0, %1" : "=v"(r) : "v"(x));
  return r;
}

__device__ __forceinline__ float frcp(float x) {
  float r;
  asm("v_rcp_f32 %0, %1" : "=v"(r) : "v"(x));
  return r;
}

// swap a's hi 32 lanes with b's lo 32 lanes
__device__ __forceinline__ void pswap(u32& a, u32& b) {
  asm("v_permlane32_swap_b32 %0, %1" : "+v"(a), "+v"(b));
}

__device__ __forceinline__ float andf(float x, u32 m) {
  union { float f; u32 u; } v; v.f = x; v.u &= m; return v.f;
}

typedef const unsigned int __attribute__((address_space(1)))* gas1_t;
typedef unsigned int __attribute__((address_space(3)))*       las3_t;

__device__ __forceinline__ void gll16(const void* g, void* l) {
  __builtin_amdgcn_global_load_lds((gas1_t)g, (las3_t)l, 16, 0, 0);
}

#define MFMA32(a, b, c) __builtin_amdgcn_mfma_f32_32x32x16_bf16((a), (b), (c), 0, 0, 0)

// ---------------- prep: cvt q/k/v -> bf16 (blocks 0..12287) + W^T (12288..13311)
__global__ __launch_bounds__(256) void prep_k(const float* __restrict__ qi, const float* __restrict__ ki,
                                              const float* __restrict__ vi, u16* __restrict__ oq,
                                              u16* __restrict__ ok, u16* __restrict__ ov,
                                              const float* __restrict__ Wq, const float* __restrict__ Wk,
                                              const float* __restrict__ Wv, const float* __restrict__ Wo,
                                              u16* __restrict__ Tq, u16* __restrict__ Tk,
                                              u16* __restrict__ Tv, u16* __restrict__ To) {
  __shared__ float tile[64][65];
  int blk = blockIdx.x;
  int t = threadIdx.x;
  if (blk < 12288) {
    const float* in; u16* out;
    if (blk < 4096) { in = qi; out = oq; }
    else if (blk < 8192) { in = ki; out = ok; blk -= 4096; }
    else { in = vi; out = ov; blk -= 8192; }
    int i = blk * 256 + t;
    const float4* p = ((const float4*)in) + (size_t)i * 2;
    float4 a = p[0], b = p[1];
    u16x8 o;
    o[0] = f2bf(a.x); o[1] = f2bf(a.y); o[2] = f2bf(a.z); o[3] = f2bf(a.w);
    o[4] = f2bf(b.x); o[5] = f2bf(b.y); o[6] = f2bf(b.z); o[7] = f2bf(b.w);
    *(((u16x8*)out) + i) = o;
    return;
  }
  int wi = blk - 12288;
  int z = wi >> 8, rem = wi & 255;
  int bx = rem & 15, by = rem >> 4;
  const float* src; u16* dst;
  switch (z) {
    case 0: src = Wq; dst = Tq; break;
    case 1: src = Wk; dst = Tk; break;
    case 2: src = Wv; dst = Tv; break;
    default: src = Wo; dst = To; break;
  }
  int k0 = bx * 64, n0 = by * 64;
#pragma unroll
  for (int it = 0; it < 4; ++it) {
    int idx = it * 256 + t;
    int r = idx >> 4, c = idx & 15;
    float4 v = *(const float4*)(src + (size_t)(k0 + r) * 1024 + n0 + c * 4);
    tile[r][c * 4 + 0] = v.x; tile[r][c * 4 + 1] = v.y;
    tile[r][c * 4 + 2] = v.z; tile[r][c * 4 + 3] = v.w;
  }
  __syncthreads();
#pragma unroll
  for (int it = 0; it < 2; ++it) {
    int idx = it * 256 + t;
    int n = idx >> 3, kc = idx & 7;
    u16x8 o;
#pragma unroll
    for (int j = 0; j < 8; ++j) o[j] = f2bf(tile[kc * 8 + j][n]);
    *(u16x8*)(dst + (size_t)(n0 + n) * 1024 + k0 + kc * 8) = o;
  }
}

// ---------------- maskpack: mask -> packed bits --------------------------------
__global__ __launch_bounds__(256) void maskpack_k(const void* __restrict__ mraw,
                                                  u64* __restrict__ mout) {
  const u32* hdr = (const u32*)mraw;
  int t = threadIdx.x;
  int lane = t & 63;
  u32 hv = hdr[lane];
  bool isf = (hv == 0x3F800000u);
  u64 bigm = __ballot(hv > 1u && !isf);
  u64 fm = __ballot(isf);
  int fmt = (__popcll(fm) > 8) ? 2 : ((bigm != 0ull) ? 0 : 1);
  size_t idx = (size_t)blockIdx.x * 256 + t;
  u64 bits = 0;
  if (fmt == 0) {
    const u64* p = (const u64*)((const uint8_t*)mraw + idx * 64);
#pragma unroll
    for (int j = 0; j < 8; ++j) {
      u64 v = p[j];
#pragma unroll
      for (int kk = 0; kk < 8; ++kk)
        bits |= (u64)(((v >> (8 * kk)) & 0xFFull) != 0) << (j * 8 + kk);
    }
  } else if (fmt == 1) {
    const int* p = ((const int*)mraw) + idx * 64;
#pragma unroll
    for (int j = 0; j < 64; ++j) bits |= (u64)(p[j] != 0) << j;
  } else {
    const u32* p = ((const u32*)mraw) + idx * 64;
#pragma unroll
    for (int j = 0; j < 64; ++j) bits |= (u64)((p[j] << 1) != 0) << j;
  }
  mout[idx] = bits;
}

// ---------------- 256x256 BK=64 8-wave pipelined GEMM body ---------------------
// Half-K-tile (32k) pipeline: stage half tau+2 while computing half tau.
// vmcnt(4) counted at each half boundary; raw s_barrier (no drain). 2 LDS bufs
// of 64KB: A k-halves @ {0,16K}, B k-halves @ {32K,48K}. Row-pair packed
// sub-tiles [128 lds-rows x 128B]; slot8 = ((r&1)*4+kk*2+l5) ^ (R&7) ^ ((R>>3)&7)
// (flash-verified 0-conflict family); stage inverts it on the global source.
__device__ __forceinline__ void gemm256_body(const u16* __restrict__ A, const u16* __restrict__ Bt,
                                             const float* __restrict__ bias, void* __restrict__ outp,
                                             float scale, int mode, int inner, char* smem) {
  int xcd = inner & 7, loc = inner >> 3;
  int mt = xcd * 4 + (loc & 3), nt = loc >> 2;   // 32 m-tiles, 4 n-tiles
  int m0 = mt * 256, n0 = nt * 256;
  int tid = threadIdx.x, w = tid >> 6, lane = tid & 63;
  int l31 = lane & 31, l5 = lane >> 5;
  int wm = w >> 2, wn = w & 3;                   // per-wave 128x64 output

  // ---- stage precompute: chunk c = q*512+tid -> (srow, skw) via inverse swizzle
  const u16* pA[2]; const u16* pB[2];
#pragma unroll
  for (int q = 0; q < 2; ++q) {
    int c = q * 512 + tid;
    int R = c >> 3, s8 = c & 7;
    int s8u = s8 ^ (R & 7) ^ ((R >> 3) & 7);
    int srow = 2 * R + (s8u >> 2), skw = s8u & 3;
    pA[q] = A  + ((size_t)(m0 + srow) << 10) + skw * 8;
    pB[q] = Bt + ((size_t)(n0 + srow) << 10) + skw * 8;
  }

  // ---- read offsets (within sub-tile region)
  int aoff[4][2], boff[2][2];
#pragma unroll
  for (int i = 0; i < 4; ++i) {
    int r = wm * 128 + i * 32 + l31;
    int R = r >> 1, sw = (R & 7) ^ ((R >> 3) & 7);
#pragma unroll
    for (int kk = 0; kk < 2; ++kk) {
      int s8 = ((r & 1) << 2) + kk * 2 + l5;
      aoff[i][kk] = R * 128 + ((s8 ^ sw) << 4);
    }
  }
#pragma unroll
  for (int j = 0; j < 2; ++j) {
    int r = wn * 64 + j * 32 + l31;
    int R = r >> 1, sw = (R & 7) ^ ((R >> 3) & 7);
#pragma unroll
    for (int kk = 0; kk < 2; ++kk) {
      int s8 = ((r & 1) << 2) + kk * 2 + l5;
      boff[j][kk] = 32768 + R * 128 + ((s8 ^ sw) << 4);
    }
  }

  f32x16 acc[4][2];
#pragma unroll
  for (int i = 0; i < 4; ++i)
#pragma unroll
    for (int j = 0; j < 2; ++j)
#pragma unroll
      for (int r = 0; r < 16; ++r) acc[i][j][r] = 0.f;

#define GSTAGE(TAU)                                                             \
  do {                                                                          \
    char* db = smem + ((((TAU) >> 1) & 1) << 16) + (((TAU) & 1) << 14) + w * 1024; \
    gll16(pA[0] + (TAU) * 32, db);                                              \
    gll16(pA[1] + (TAU) * 32, db + 8192);                                       \
    gll16(pB[0] + (TAU) * 32, db + 32768);                                      \
    gll16(pB[1] + (TAU) * 32, db + 40960);                                      \
  } while (0)

#define GCOMPUTE(TAU)                                                           \
  do {                                                                          \
    const char* base = smem + ((((TAU) >> 1) & 1) << 16) + (((TAU) & 1) << 14); \
    BF8 af[4][2], bf_[2][2];                                                    \
    _Pragma("unroll") for (int kk = 0; kk < 2; ++kk) {                          \
      _Pragma("unroll") for (int i = 0; i < 4; ++i)                             \
        af[i][kk].u = *(const u16x8*)(base + aoff[i][kk]);                      \
      _Pragma("unroll") for (int j = 0; j < 2; ++j)                             \
        bf_[j][kk].u = *(const u16x8*)(base + boff[j][kk]);                     \
    }                                                                           \
    __builtin_amdgcn_s_setprio(1);                                              \
    _Pragma("unroll") for (int kk = 0; kk < 2; ++kk)                            \
      _Pragma("unroll") for (int i = 0; i < 4; ++i)                             \
        _Pragma("unroll") for (int j = 0; j < 2; ++j)                           \
          acc[i][j] = MFMA32(af[i][kk].b, bf_[j][kk].b, acc[i][j]);             \
    __builtin_amdgcn_s_setprio(0);                                              \
  } while (0)

  GSTAGE(0);
  GSTAGE(1);
#pragma unroll 2
  for (int tau = 0; tau < 31; ++tau) {
    asm volatile("s_waitcnt vmcnt(4)" ::: "memory");
    __builtin_amdgcn_s_barrier();
    __builtin_amdgcn_sched_barrier(0);
    if (tau < 30) GSTAGE(tau + 2);
    GCOMPUTE(tau);
  }
  asm volatile("s_waitcnt vmcnt(0)" ::: "memory");
  __builtin_amdgcn_s_barrier();
  __builtin_amdgcn_sched_barrier(0);
  GCOMPUTE(31);
#undef GSTAGE
#undef GCOMPUTE

  // ---- epilogue
#pragma unroll
  for (int i = 0; i < 4; ++i)
#pragma unroll
    for (int j = 0; j < 2; ++j) {
      int gcol = n0 + wn * 64 + j * 32 + l31;
      float bv = bias[gcol];
      if (mode == 1) {
        // V: direct-transpose store, 4 consecutive s per u16x4
        int hh = gcol >> 6, hd = gcol & 63;
#pragma unroll
        for (int qd = 0; qd < 4; ++qd) {
          int grow = m0 + wm * 128 + i * 32 + qd * 8 + l5 * 4;
          int bb = grow >> 11, s = grow & 2047;
          u16x4 ov;
#pragma unroll
          for (int rr = 0; rr < 4; ++rr) ov[rr] = f2bf(acc[i][j][qd * 4 + rr] + bv);
          *(u16x4*)((u16*)outp + (((size_t)bb * H_ + hh) * HD_ + hd) * S_ + s) = ov;
        }
      } else if (mode == 0) {
        int hh = gcol >> 6, hd = gcol & 63;
#pragma unroll
        for (int reg = 0; reg < 16; ++reg) {
          int grow = m0 + wm * 128 + i * 32 + (reg & 3) + 8 * (reg >> 2) + 4 * l5;
          int bb = grow >> 11, s = grow & 2047;
          ((u16*)outp)[(((size_t)bb * H_ + hh) * S_ + s) * HD_ + hd] =
              f2bf((acc[i][j][reg] + bv) * scale);
        }
      } else {
#pragma unroll
        for (int reg = 0; reg < 16; ++reg) {
          int grow = m0 + wm * 128 + i * 32 + (reg & 3) + 8 * (reg >> 2) + 4 * l5;
          ((float*)outp)[(size_t)grow * 1024 + gcol] = acc[i][j][reg] + bv;
        }
      }
    }
}

// ---------------- fused Q/K/V projections: 3 x 128 blocks ----------------------
__global__ __launch_bounds__(512) void proj3n_k(const u16* __restrict__ Aq, const u16* __restrict__ Ak,
                                                const u16* __restrict__ Av,
                                                const u16* __restrict__ Tq, const u16* __restrict__ Tk,
                                                const u16* __restrict__ Tv,
                                                const float* __restrict__ bq, const float* __restrict__ bk,
                                                const float* __restrict__ bv,
                                                u16* __restrict__ Qh, u16* __restrict__ Kh,
                                                u16* __restrict__ Vt, float qscale) {
  __shared__ __align__(16) char smem[131072];
  int bid = blockIdx.x;
  int g = bid >> 7, inner = bid & 127;
  const u16* A; const u16* Bt; const float* bias; void* outp; float scale; int mode;
  if (g == 0)      { A = Aq; Bt = Tq; bias = bq; outp = Qh; scale = qscale; mode = 0; }
  else if (g == 1) { A = Ak; Bt = Tk; bias = bk; outp = Kh; scale = 1.0f;  mode = 0; }
  else             { A = Av; Bt = Tv; bias = bv; outp = Vt; scale = 1.0f;  mode = 1; }
  gemm256_body(A, Bt, bias, outp, scale, mode, inner, smem);
}

// ---------------- final output GEMM: f32 out -----------------------------------
__global__ __launch_bounds__(512) void gemmo2_k(const u16* __restrict__ A,
                                                const u16* __restrict__ Bt,
                                                const float* __restrict__ bias,
                                                float* __restrict__ outp) {
  __shared__ __align__(16) char smem[131072];
  gemm256_body(A, Bt, bias, outp, 1.0f, 2, blockIdx.x, smem);
}

// ---------------- flash attention: no-max softmax (bounded scores) -------------
__global__ __launch_bounds__(256) void flash_k(const u16* __restrict__ Qh,
                                               const u16* __restrict__ Kh,
                                               const u16* __restrict__ Vt,
                                               const u64* __restrict__ mb,
                                               u16* __restrict__ ctx) {
  int bid = blockIdx.x;
  int xcd = bid & 7, loc = bid >> 3;
  int bh = xcd * 8 + (loc & 7);
  int qblk = loc >> 3;
  int b = bh >> 4, h = bh & 15;
  int t = threadIdx.x, w = t >> 6, lane = t & 63;
  int l31 = lane & 31, l5 = lane >> 5;
  __shared__ __align__(16) char smem[32768];

  int q0 = qblk * 128 + w * 32;
  const u16* kbase = Kh + (size_t)bh * S_ * HD_;
  const u16* vbase = Vt + (size_t)bh * HD_ * S_;
  const uint2* mrow = ((const uint2*)mb) + ((size_t)b * S_ + q0 + l31) * 32;

  const u16* qbase = Qh + ((size_t)bh * S_ + q0 + l31) * HD_;
  BF8 qf[4];
#pragma unroll
  for (int dk = 0; dk < 4; ++dk) qf[dk].u = *(const u16x8*)(qbase + dk * 16 + l5 * 8);

  int koff0[4], koffB[4];
#pragma unroll
  for (int dk = 0; dk < 4; ++dk) {
    int s0_ = (dk * 2 + l5) ^ (l31 & 7) ^ (l31 >> 3);
    koff0[dk] = l31 * 128 + s0_ * 16;
    koffB[dk] = 4096 + l31 * 128 + ((s0_ ^ 4) * 16);
  }

  BF8 onesf;
#pragma unroll
  for (int i = 0; i < 8; ++i) onesf.u[i] = 0x3F80;

  f32x16 o0, o1, lac, zv;
#pragma unroll
  for (int r = 0; r < 16; ++r) { o0[r] = 0.f; o1[r] = 0.f; lac[r] = 0.f; zv[r] = 0.f; }

#define STAGE(KT, BUF)                                                          \
  do {                                                                          \
    char* Kd = smem + (BUF);                                                    \
    int k0s = (KT) * 64;                                                        \
    _Pragma("unroll") for (int i_ = 0; i_ < 2; ++i_) {                          \
      int c_ = i_ * 256 + t;                                                    \
      int row_ = c_ >> 3, sl_ = c_ & 7;                                         \
      int sc_ = sl_ ^ (row_ & 7) ^ (row_ >> 3);                                 \
      int cw_ = (i_ * 256 + w * 64) * 16;                                       \
      gll16(kbase + (size_t)(k0s + row_) * HD_ + sc_ * 8, Kd + cw_);            \
      gll16(vbase + (size_t)row_ * S_ + k0s + sc_ * 8, Kd + 8192 + cw_);        \
    }                                                                           \
  } while (0)

#define MKFRAG(FR, A0, B0, C0, D0)                                              \
  do {                                                                          \
    u32 xx0 = (A0), xx1 = (C0), yy0 = (B0), yy1 = (D0);                         \
    pswap(xx0, xx1); pswap(yy0, yy1);                                           \
    FR.w[0] = xx0; FR.w[1] = yy0; FR.w[2] = xx1; FR.w[3] = yy1;                 \
  } while (0)

#define PVS(FR, KC)                                                             \
  do {                                                                          \
    lac = MFMA32(FR.b, onesf.b, lac);                                           \
    BF8 vf0, vf1;                                                               \
    vf0.u = *(const u16x8*)(Kb + 8192 + koff0[(KC)]);                           \
    vf1.u = *(const u16x8*)(Kb + 8192 + koffB[(KC)]);                           \
    o0 = MFMA32(FR.b, vf0.b, o0);                                               \
    o1 = MFMA32(FR.b, vf1.b, o1);                                               \
  } while (0)

#define FTILE(KT, BUF, OBUF, ISLAST)                                            \
  {                                                                             \
    __syncthreads();                                                            \
    uint2 mw = mrow[(KT)];                                                      \
    if (!(ISLAST)) STAGE((KT) + 1, OBUF);                                       \
    const char* Kb = smem + (BUF);                                              \
    f32x16 sa0, sa1;                                                            \
    __builtin_amdgcn_s_setprio(1);                                              \
    {                                                                           \
      BF8 kf0, kf1;                                                             \
      kf0.u = *(const u16x8*)(Kb + koff0[0]);                                   \
      kf1.u = *(const u16x8*)(Kb + koffB[0]);                                   \
      sa0 = MFMA32(kf0.b, qf[0].b, zv);                                         \
      sa1 = MFMA32(kf1.b, qf[0].b, zv);                                         \
    }                                                                           \
    _Pragma("unroll") for (int dk = 1; dk < 4; ++dk) {                          \
      BF8 kf0, kf1;                                                             \
      kf0.u = *(const u16x8*)(Kb + koff0[dk]);                                  \
      kf1.u = *(const u16x8*)(Kb + koffB[dk]);                                  \
      sa0 = MFMA32(kf0.b, qf[dk].b, sa0);                                       \
      sa1 = MFMA32(kf1.b, qf[dk].b, sa1);                                       \
    }                                                                           \
    __builtin_amdgcn_s_setprio(0);                                              \
    u32 nw0 = ~(mw.x >> (l5 * 4));                                              \
    u32 nw1 = ~(mw.y >> (l5 * 4));                                              \
    _Pragma("unroll") for (int r = 0; r < 16; ++r) {                            \
      const int pp = (r & 3) + 8 * (r >> 2);                                    \
      sa0[r] = andf(fexp2(sa0[r]), (u32)__builtin_amdgcn_sbfe((int)nw0, pp, 1));\
      sa1[r] = andf(fexp2(sa1[r]), (u32)__builtin_amdgcn_sbfe((int)nw1, pp, 1));\
    }                                                                           \
    u32 pk0[8], pk1[8];                                                         \
    _Pragma("unroll") for (int i = 0; i < 8; ++i) {                             \
      pk0[i] = cvtpk(sa0[2 * i], sa0[2 * i + 1]);                               \
      pk1[i] = cvtpk(sa1[2 * i], sa1[2 * i + 1]);                               \
    }                                                                           \
    BF8 fr0, fr1, fr2, fr3;                                                     \
    MKFRAG(fr0, pk0[0], pk0[1], pk0[2], pk0[3]);                                \
    MKFRAG(fr1, pk0[4], pk0[5], pk0[6], pk0[7]);                                \
    MKFRAG(fr2, pk1[0], pk1[1], pk1[2], pk1[3]);                                \
    MKFRAG(fr3, pk1[4], pk1[5], pk1[6], pk1[7]);                                \
    __builtin_amdgcn_s_setprio(1);                                              \
    PVS(fr0, 0); PVS(fr1, 1); PVS(fr2, 2); PVS(fr3, 3);                         \
    __builtin_amdgcn_s_setprio(0);                                              \
  }

  STAGE(0, 0);
  for (int kt2 = 0; kt2 < 16; ++kt2) {
    FTILE(2 * kt2, 0, 16384, false);
    FTILE(2 * kt2 + 1, 16384, 0, (kt2 == 15));
  }

#pragma unroll
  for (int r = 0; r < 16; ++r) {
    float inv = frcp(lac[r] + 1e-35f);
    int q = (r & 3) + 8 * (r >> 2) + 4 * l5;
    size_t base = ((size_t)b * S_ + q0 + q) * D_ + h * HD_;
    ctx[base + l31]      = f2bf(o0[r] * inv);
    ctx[base + 32 + l31] = f2bf(o1[r] * inv);
  }
#undef STAGE
#undef MKFRAG
#undef PVS
#undef FTILE
}

extern "C" void kernel_launch(void* const* d_in, const int* in_sizes, int n_in,
                              void* d_out, int out_size, void* d_ws, size_t ws_size,
                              hipStream_t stream) {
  (void)in_sizes; (void)n_in; (void)out_size; (void)ws_size;
  const float* q  = (const float*)d_in[0];
  const float* k  = (const float*)d_in[1];
  const float* v  = (const float*)d_in[2];
  const void*  mk = d_in[3];
  const float* Wq = (const float*)d_in[4];
  const float* bq = (const float*)d_in[5];
  const float* Wk = (const float*)d_in[6];
  const float* bk = (const float*)d_in[7];
  const float* Wv = (const float*)d_in[8];
  const float* bv = (const float*)d_in[9];
  const float* Wo = (const float*)d_in[10];
  const float* bo = (const float*)d_in[11];

  char* ws = (char*)d_ws;
  u16* qb   = (u16*)(ws + 0);
  u16* kbuf = (u16*)(ws + 16777216);   // reused as ctx after proj3n
  u16* vbuf = (u16*)(ws + 33554432);   // reused as packed mask after proj3n
  u16* Tq   = (u16*)(ws + 50331648);
  u16* Tk   = (u16*)(ws + 52428800);
  u16* Tv   = (u16*)(ws + 54525952);
  u16* To   = (u16*)(ws + 56623104);
  u16* Qh   = (u16*)(ws + 58720256);
  u16* Kh   = (u16*)(ws + 75497472);
  u16* Vt   = (u16*)(ws + 92274688);   // V written transposed directly
  u16* ctx  = kbuf;
  u64* mc   = (u64*)vbuf;

  const float QSCALE = 0.18033688011112042f;  // (1/8) * log2(e)

  prep_k<<<13312, 256, 0, stream>>>(q, k, v, qb, kbuf, vbuf,
                                    Wq, Wk, Wv, Wo, Tq, Tk, Tv, To);
  proj3n_k<<<384, 512, 0, stream>>>(qb, kbuf, vbuf, Tq, Tk, Tv,
                                    bq, bk, bv, Qh, Kh, Vt, QSCALE);
  maskpack_k<<<1024, 256, 0, stream>>>(mk, mc);
  flash_k<<<1024, 256, 0, stream>>>(Qh, Kh, Vt, mc, ctx);
  gemmo2_k<<<128, 512, 0, stream>>>(ctx, To, bo, (float*)d_out);
}